// Round 1
// baseline (549.184 us; speedup 1.0000x reference)
//
#include <hip/hip_runtime.h>
#include <stdint.h>

// ReviewLoss: ce[i] = logsumexp(out[i,:]) - out[i, target[i]]
//   lam = k-th (0-indexed, descending) order statistic of ce, k = int(N*0.3)
//   result = mean over ALL N of (ce >= lam ? ce : 0)
//
// Design:
//   Kernel 1 (memory-bound, ~131 MB read): one wave per row. float4 loads,
//     wave shuffle reductions for max and sum-exp. Writes ce[i] to ws and
//     builds a 2048-bin global histogram of the top 11 bits of ce's IEEE
//     pattern (ce >= 0 so uint bit order == value order).
//   Kernel 2 (single block, 1024 threads): hierarchical radix-select on the
//     remaining bits (11 + 10) via LDS histograms + block suffix scans, then
//     sums all ce >= lam in double and writes the mean.

typedef unsigned int uint32;

__global__ __launch_bounds__(256) void ce_kernel(
    const float* __restrict__ logits, const int* __restrict__ target,
    float* __restrict__ ce, uint32* __restrict__ ghist, int N, int C) {
  int wave = (int)((blockIdx.x * blockDim.x + threadIdx.x) >> 6);
  int lane = (int)(threadIdx.x & 63);
  if (wave >= N) return;

  const float* row = logits + (size_t)wave * (size_t)C;
  const float4* row4 = (const float4*)row;
  const int nv4 = C >> 2;  // C assumed % 4 == 0 (C = 1000)

  // Up to 4 iterations covers C <= 1024.
  float4 v[4];
#pragma unroll
  for (int j = 0; j < 4; ++j) {
    int c4 = lane + 64 * j;
    if (c4 < nv4) {
      v[j] = row4[c4];
    } else {
      v[j] = make_float4(-INFINITY, -INFINITY, -INFINITY, -INFINITY);
    }
  }

  // Row max
  float m = -INFINITY;
#pragma unroll
  for (int j = 0; j < 4; ++j) {
    m = fmaxf(m, fmaxf(fmaxf(v[j].x, v[j].y), fmaxf(v[j].z, v[j].w)));
  }
#pragma unroll
  for (int off = 1; off < 64; off <<= 1) m = fmaxf(m, __shfl_xor(m, off));

  // Sum of exp(x - m); padding lanes hold -inf -> exp = 0
  float ssum = 0.0f;
#pragma unroll
  for (int j = 0; j < 4; ++j) {
    ssum += __expf(v[j].x - m);
    ssum += __expf(v[j].y - m);
    ssum += __expf(v[j].z - m);
    ssum += __expf(v[j].w - m);
  }
#pragma unroll
  for (int off = 1; off < 64; off <<= 1) ssum += __shfl_xor(ssum, off);

  int t = target[wave];
  float ot = row[t];  // same address on all 64 lanes -> HW broadcast

  float cev = (m - ot) + __logf(ssum);
  cev = fmaxf(cev, 0.0f);  // guard -0.0 / tiny negatives; ce >= 0 analytically

  if (lane == 0) {
    ce[wave] = cev;
    atomicAdd(&ghist[__float_as_uint(cev) >> 21], 1u);
  }
}

// Inclusive suffix sum over s[0..n) (n <= 2048), 1024 threads.
// Caller must __syncthreads() before calling.
__device__ __forceinline__ void suffix_scan(uint32* s, int n, int tid) {
  for (int off = 1; off < n; off <<= 1) {
    uint32 a = 0, b = 0;
    int i0 = tid, i1 = tid + 1024;
    if (i0 < n) a = s[i0] + ((i0 + off < n) ? s[i0 + off] : 0u);
    if (i1 < n) b = s[i1] + ((i1 + off < n) ? s[i1 + off] : 0u);
    __syncthreads();
    if (i0 < n) s[i0] = a;
    if (i1 < n) s[i1] = b;
    __syncthreads();
  }
}

__global__ __launch_bounds__(1024) void select_kernel(
    const float* __restrict__ ce, const uint32* __restrict__ ghist,
    float* __restrict__ out, int N, int k) {
  __shared__ uint32 h[2048];
  __shared__ uint32 s[2048];
  __shared__ uint32 sel[2];
  __shared__ double wsum[16];
  const int tid = (int)threadIdx.x;
  const uint32 kk0 = (uint32)k;

  // ---- Level 1: top 11 bits (histogram built by ce_kernel) ----
  h[tid] = ghist[tid];
  h[tid + 1024] = ghist[tid + 1024];
  s[tid] = h[tid];
  s[tid + 1024] = h[tid + 1024];
  __syncthreads();
  suffix_scan(s, 2048, tid);
  for (int i = tid; i < 2048; i += 1024) {
    uint32 SG = (i + 1 < 2048) ? s[i + 1] : 0u;  // count strictly greater
    if (SG <= kk0 && kk0 < s[i]) { sel[0] = (uint32)i; sel[1] = kk0 - SG; }
  }
  __syncthreads();
  const uint32 B1 = sel[0];
  const uint32 k1 = sel[1];
  __syncthreads();

  // ---- Level 2: bits 20..10 ----
  h[tid] = 0; h[tid + 1024] = 0;
  __syncthreads();
  for (int i = tid; i < N; i += 1024) {
    uint32 u = __float_as_uint(ce[i]);
    if ((u >> 21) == B1) atomicAdd(&h[(u >> 10) & 2047u], 1u);
  }
  __syncthreads();
  s[tid] = h[tid];
  s[tid + 1024] = h[tid + 1024];
  __syncthreads();
  suffix_scan(s, 2048, tid);
  for (int i = tid; i < 2048; i += 1024) {
    uint32 SG = (i + 1 < 2048) ? s[i + 1] : 0u;
    if (SG <= k1 && k1 < s[i]) { sel[0] = (uint32)i; sel[1] = k1 - SG; }
  }
  __syncthreads();
  const uint32 B2 = sel[0];
  const uint32 k2 = sel[1];
  __syncthreads();

  // ---- Level 3: bits 9..0 ----
  h[tid] = 0;
  __syncthreads();
  const uint32 pre = (B1 << 11) | B2;
  for (int i = tid; i < N; i += 1024) {
    uint32 u = __float_as_uint(ce[i]);
    if ((u >> 10) == pre) atomicAdd(&h[u & 1023u], 1u);
  }
  __syncthreads();
  s[tid] = h[tid];
  __syncthreads();
  suffix_scan(s, 1024, tid);
  {
    int i = tid;  // 1024 bins, 1024 threads
    uint32 SG = (i + 1 < 1024) ? s[i + 1] : 0u;
    if (SG <= k2 && k2 < s[i]) sel[0] = (uint32)i;
  }
  __syncthreads();
  const uint32 lam_u = (pre << 10) | sel[0];

  // ---- Sum of all ce >= lam (bit order == value order for ce >= 0) ----
  double acc = 0.0;
  for (int i = tid; i < N; i += 1024) {
    float x = ce[i];
    if (__float_as_uint(x) >= lam_u) acc += (double)x;
  }
#pragma unroll
  for (int off = 1; off < 64; off <<= 1) acc += __shfl_xor(acc, off);
  if ((tid & 63) == 0) wsum[tid >> 6] = acc;
  __syncthreads();
  if (tid == 0) {
    double t = 0.0;
    for (int i = 0; i < 16; ++i) t += wsum[i];
    out[0] = (float)(t / (double)N);
  }
}

extern "C" void kernel_launch(void* const* d_in, const int* in_sizes, int n_in,
                              void* d_out, int out_size, void* d_ws, size_t ws_size,
                              hipStream_t stream) {
  const float* logits = (const float*)d_in[0];
  const int* target = (const int*)d_in[1];
  float* out = (float*)d_out;

  const int N = in_sizes[1];            // 32768
  const int C = in_sizes[0] / N;        // 1000

  float* ce = (float*)d_ws;
  uint32* ghist = (uint32*)((char*)d_ws + (size_t)N * sizeof(float));

  // Zero the level-1 histogram (ws is re-poisoned to 0xAA each launch).
  hipMemsetAsync(ghist, 0, 2048 * sizeof(uint32), stream);

  // Kernel 1: one wave per row, 4 rows per 256-thread block.
  int grid = (N + 3) / 4;
  ce_kernel<<<grid, 256, 0, stream>>>(logits, target, ce, ghist, N, C);

  // k = int(N * 0.3)
  int k = (int)((double)N * 0.3);

  // Kernel 2: single block does radix refine + filtered mean.
  select_kernel<<<1, 1024, 0, stream>>>(ce, ghist, out, N, k);
}

// Round 2
// 531.589 us; speedup vs baseline: 1.0331x; 1.0331x over previous
//
#include <hip/hip_runtime.h>
#include <stdint.h>

// ReviewLoss: ce[i] = logsumexp(out[i,:]) - out[i, target[i]]
//   lam = k-th (0-indexed, descending) order statistic of ce, k = int(N*0.3)
//   result = mean over ALL N of (ce >= lam ? ce : 0)
//
// Kernel 1: one 256-thread block per row, ONE float4 per thread held in
//   registers for both the max pass and the exp pass (no register array ->
//   no scratch demotion, the R1 failure mode). Two barriers per block.
// Kernel 2: single 1024-thread block; 3-level radix select on the IEEE bit
//   pattern (ce >= 0 so uint order == value order), float4-vectorized
//   passes, then filtered mean in double.

typedef unsigned int uint32;

__global__ __launch_bounds__(256) void ce_kernel(
    const float* __restrict__ logits, const int* __restrict__ target,
    float* __restrict__ ce, uint32* __restrict__ ghist, int N, int C) {
  const int row = (int)blockIdx.x;
  const int tid = (int)threadIdx.x;
  const int lane = tid & 63;
  const int wid = tid >> 6;

  const float* rp = logits + (size_t)row * (size_t)C;

  // Independent early loads (same address across threads -> broadcast).
  const int t = target[row];
  const float ot = rp[t];

  const int nv4 = C >> 2;  // C % 4 == 0 (C = 1000 -> 250 quads, threads 250..255 idle)
  float4 v;
  if (tid < nv4) {
    v = ((const float4*)rp)[tid];
  } else {
    v = make_float4(-INFINITY, -INFINITY, -INFINITY, -INFINITY);
  }

  __shared__ float redmax[4];
  __shared__ float redsum[4];

  // Block max
  float m = fmaxf(fmaxf(v.x, v.y), fmaxf(v.z, v.w));
#pragma unroll
  for (int off = 1; off < 64; off <<= 1) m = fmaxf(m, __shfl_xor(m, off));
  if (lane == 0) redmax[wid] = m;
  __syncthreads();
  m = fmaxf(fmaxf(redmax[0], redmax[1]), fmaxf(redmax[2], redmax[3]));

  // Sum of exp(x - m); idle threads hold -inf -> exp = 0
  float e = __expf(v.x - m) + __expf(v.y - m) + __expf(v.z - m) + __expf(v.w - m);
#pragma unroll
  for (int off = 1; off < 64; off <<= 1) e += __shfl_xor(e, off);
  if (lane == 0) redsum[wid] = e;
  __syncthreads();

  if (tid == 0) {
    float ssum = redsum[0] + redsum[1] + redsum[2] + redsum[3];
    float cev = (m - ot) + __logf(ssum);
    cev = fmaxf(cev, 0.0f);  // ce >= 0 analytically; kill -0.0
    ce[row] = cev;
    atomicAdd(&ghist[__float_as_uint(cev) >> 21], 1u);
  }
}

// Inclusive suffix sum over s[0..n) (n <= 2048), 1024 threads, in place.
// Caller must __syncthreads() before calling.
__device__ __forceinline__ void suffix_scan(uint32* s, int n, int tid) {
  for (int off = 1; off < n; off <<= 1) {
    uint32 a = 0, b = 0;
    int i0 = tid, i1 = tid + 1024;
    if (i0 < n) a = s[i0] + ((i0 + off < n) ? s[i0 + off] : 0u);
    if (i1 < n) b = s[i1] + ((i1 + off < n) ? s[i1 + off] : 0u);
    __syncthreads();
    if (i0 < n) s[i0] = a;
    if (i1 < n) s[i1] = b;
    __syncthreads();
  }
}

__global__ __launch_bounds__(1024) void select_kernel(
    const float* __restrict__ ce, const uint32* __restrict__ ghist,
    float* __restrict__ out, int N, int k) {
  __shared__ uint32 s[2048];
  __shared__ uint32 sel[2];
  __shared__ double wsum[16];
  const int tid = (int)threadIdx.x;
  const uint32 kk0 = (uint32)k;
  const float4* ce4 = (const float4*)ce;
  const int N4 = N >> 2;  // N % 4 == 0

  // ---- Level 1: top 11 bits (global histogram built by ce_kernel) ----
  s[tid] = ghist[tid];
  s[tid + 1024] = ghist[tid + 1024];
  __syncthreads();
  suffix_scan(s, 2048, tid);
  for (int i = tid; i < 2048; i += 1024) {
    uint32 SG = (i + 1 < 2048) ? s[i + 1] : 0u;  // count strictly greater
    if (SG <= kk0 && kk0 < s[i]) { sel[0] = (uint32)i; sel[1] = kk0 - SG; }
  }
  __syncthreads();
  const uint32 B1 = sel[0];
  const uint32 k1 = sel[1];
  __syncthreads();

  // ---- Level 2: bits 20..10 ----
  s[tid] = 0; s[tid + 1024] = 0;
  __syncthreads();
  for (int i = tid; i < N4; i += 1024) {
    float4 x = ce4[i];
    uint32 u0 = __float_as_uint(x.x), u1 = __float_as_uint(x.y);
    uint32 u2 = __float_as_uint(x.z), u3 = __float_as_uint(x.w);
    if ((u0 >> 21) == B1) atomicAdd(&s[(u0 >> 10) & 2047u], 1u);
    if ((u1 >> 21) == B1) atomicAdd(&s[(u1 >> 10) & 2047u], 1u);
    if ((u2 >> 21) == B1) atomicAdd(&s[(u2 >> 10) & 2047u], 1u);
    if ((u3 >> 21) == B1) atomicAdd(&s[(u3 >> 10) & 2047u], 1u);
  }
  __syncthreads();
  suffix_scan(s, 2048, tid);
  for (int i = tid; i < 2048; i += 1024) {
    uint32 SG = (i + 1 < 2048) ? s[i + 1] : 0u;
    if (SG <= k1 && k1 < s[i]) { sel[0] = (uint32)i; sel[1] = k1 - SG; }
  }
  __syncthreads();
  const uint32 B2 = sel[0];
  const uint32 k2 = sel[1];
  __syncthreads();

  // ---- Level 3: bits 9..0 ----
  s[tid] = 0;
  __syncthreads();
  const uint32 pre = (B1 << 11) | B2;
  for (int i = tid; i < N4; i += 1024) {
    float4 x = ce4[i];
    uint32 u0 = __float_as_uint(x.x), u1 = __float_as_uint(x.y);
    uint32 u2 = __float_as_uint(x.z), u3 = __float_as_uint(x.w);
    if ((u0 >> 10) == pre) atomicAdd(&s[u0 & 1023u], 1u);
    if ((u1 >> 10) == pre) atomicAdd(&s[u1 & 1023u], 1u);
    if ((u2 >> 10) == pre) atomicAdd(&s[u2 & 1023u], 1u);
    if ((u3 >> 10) == pre) atomicAdd(&s[u3 & 1023u], 1u);
  }
  __syncthreads();
  suffix_scan(s, 1024, tid);
  {
    int i = tid;  // 1024 bins, 1024 threads
    uint32 SG = (i + 1 < 1024) ? s[i + 1] : 0u;
    if (SG <= k2 && k2 < s[i]) sel[0] = (uint32)i;
  }
  __syncthreads();
  const uint32 lam_u = (pre << 10) | sel[0];

  // ---- Sum of all ce >= lam (bit order == value order for ce >= 0) ----
  double acc = 0.0;
  for (int i = tid; i < N4; i += 1024) {
    float4 x = ce4[i];
    if (__float_as_uint(x.x) >= lam_u) acc += (double)x.x;
    if (__float_as_uint(x.y) >= lam_u) acc += (double)x.y;
    if (__float_as_uint(x.z) >= lam_u) acc += (double)x.z;
    if (__float_as_uint(x.w) >= lam_u) acc += (double)x.w;
  }
#pragma unroll
  for (int off = 1; off < 64; off <<= 1) acc += __shfl_xor(acc, off);
  if ((tid & 63) == 0) wsum[tid >> 6] = acc;
  __syncthreads();
  if (tid == 0) {
    double tsum = 0.0;
    for (int i = 0; i < 16; ++i) tsum += wsum[i];
    out[0] = (float)(tsum / (double)N);
  }
}

extern "C" void kernel_launch(void* const* d_in, const int* in_sizes, int n_in,
                              void* d_out, int out_size, void* d_ws, size_t ws_size,
                              hipStream_t stream) {
  const float* logits = (const float*)d_in[0];
  const int* target = (const int*)d_in[1];
  float* out = (float*)d_out;

  const int N = in_sizes[1];            // 32768
  const int C = in_sizes[0] / N;        // 1000

  float* ce = (float*)d_ws;
  uint32* ghist = (uint32*)((char*)d_ws + (size_t)N * sizeof(float));

  // Zero the level-1 histogram (ws is re-poisoned to 0xAA each launch).
  hipMemsetAsync(ghist, 0, 2048 * sizeof(uint32), stream);

  // Kernel 1: one 256-thread block per row.
  ce_kernel<<<N, 256, 0, stream>>>(logits, target, ce, ghist, N, C);

  // k = int(N * 0.3)
  int k = (int)((double)N * 0.3);

  // Kernel 2: single block does radix refine + filtered mean.
  select_kernel<<<1, 1024, 0, stream>>>(ce, ghist, out, N, k);
}

// Round 3
// 223.648 us; speedup vs baseline: 2.4556x; 2.3769x over previous
//
#include <hip/hip_runtime.h>
#include <stdint.h>

// ReviewLoss: ce[i] = logsumexp(out[i,:]) - out[i, target[i]]
//   lam = k-th (0-indexed, descending) order statistic of ce, k = int(N*0.3)
//   result = mean over ALL N of (ce >= lam ? ce : 0)
//
// R2 post-mortem: the per-row global atomicAdd into the 2048-bin histogram
// was the entire 378 us runtime — ce values concentrate into ~3 exponent
// bins, so 32768 device-scope atomics serialized on ~3 L2 lines (WRITE_SIZE
// = 2048 KB = 32768 x 64 B dirty lines; duration invariant under L3-hot
// replays). Fix: no global histogram. select_kernel builds the level-1
// histogram from the 128 KB ce array with wave-aggregated LDS atomics.

typedef unsigned int uint32;

__global__ __launch_bounds__(256) void ce_kernel(
    const float* __restrict__ logits, const int* __restrict__ target,
    float* __restrict__ ce, int N, int C) {
  const int row = (int)blockIdx.x;
  const int tid = (int)threadIdx.x;
  const int lane = tid & 63;
  const int wid = tid >> 6;

  const float* rp = logits + (size_t)row * (size_t)C;

  // Uniform loads (broadcast); issued early.
  const int t = target[row];
  const float ot = rp[t];

  const int nv4 = C >> 2;  // C % 4 == 0 (C=1000 -> 250 quads; threads 250..255 idle)
  float4 v;
  if (tid < nv4) {
    v = ((const float4*)rp)[tid];
  } else {
    v = make_float4(-INFINITY, -INFINITY, -INFINITY, -INFINITY);
  }

  __shared__ float redmax[4];
  __shared__ float redsum[4];

  // Block max
  float m = fmaxf(fmaxf(v.x, v.y), fmaxf(v.z, v.w));
#pragma unroll
  for (int off = 1; off < 64; off <<= 1) m = fmaxf(m, __shfl_xor(m, off));
  if (lane == 0) redmax[wid] = m;
  __syncthreads();
  m = fmaxf(fmaxf(redmax[0], redmax[1]), fmaxf(redmax[2], redmax[3]));

  // Sum of exp(x - m); idle threads hold -inf -> exp = 0
  float e = __expf(v.x - m) + __expf(v.y - m) + __expf(v.z - m) + __expf(v.w - m);
#pragma unroll
  for (int off = 1; off < 64; off <<= 1) e += __shfl_xor(e, off);
  if (lane == 0) redsum[wid] = e;
  __syncthreads();

  if (tid == 0) {
    float ssum = redsum[0] + redsum[1] + redsum[2] + redsum[3];
    float cev = (m - ot) + __logf(ssum);
    cev = fmaxf(cev, 0.0f);  // ce >= 0 analytically; kill -0.0
    ce[row] = cev;
  }
}

// Wave-aggregated histogram add: one LDS atomic per DISTINCT bin per wave.
// All 64 lanes must be active (uniform control flow).
__device__ __forceinline__ void wave_hist_add(uint32* h, uint32 bin, int lane) {
  bool done = false;
  while (true) {
    unsigned long long pend = __ballot(!done);
    if (pend == 0ull) break;
    int src = (int)__ffsll((unsigned long long)pend) - 1;
    uint32 b = (uint32)__shfl((int)bin, src);
    bool mine = (!done) && (bin == b);
    unsigned long long m = __ballot(mine);
    if (lane == src) atomicAdd(&h[b], (uint32)__popcll(m));
    if (mine) done = true;
  }
}

// Inclusive suffix sum over s[0..n) (n <= 2048), 1024 threads, in place.
// Caller must __syncthreads() before calling.
__device__ __forceinline__ void suffix_scan(uint32* s, int n, int tid) {
  for (int off = 1; off < n; off <<= 1) {
    uint32 a = 0, b = 0;
    int i0 = tid, i1 = tid + 1024;
    if (i0 < n) a = s[i0] + ((i0 + off < n) ? s[i0 + off] : 0u);
    if (i1 < n) b = s[i1] + ((i1 + off < n) ? s[i1 + off] : 0u);
    __syncthreads();
    if (i0 < n) s[i0] = a;
    if (i1 < n) s[i1] = b;
    __syncthreads();
  }
}

__global__ __launch_bounds__(1024) void select_kernel(
    const float* __restrict__ ce, float* __restrict__ out, int N, int k) {
  __shared__ uint32 s[2048];
  __shared__ uint32 sel[2];
  __shared__ double wsum[16];
  const int tid = (int)threadIdx.x;
  const int lane = tid & 63;
  const uint32 kk0 = (uint32)k;
  const float4* ce4 = (const float4*)ce;
  const int N4 = N >> 2;  // N % 4 == 0

  // ---- Level 1: top 11 bits; wave-aggregated LDS atomics (hot bins!) ----
  s[tid] = 0; s[tid + 1024] = 0;
  __syncthreads();
  for (int i = tid; i < N4; i += 1024) {
    float4 x = ce4[i];
    wave_hist_add(s, __float_as_uint(x.x) >> 21, lane);
    wave_hist_add(s, __float_as_uint(x.y) >> 21, lane);
    wave_hist_add(s, __float_as_uint(x.z) >> 21, lane);
    wave_hist_add(s, __float_as_uint(x.w) >> 21, lane);
  }
  __syncthreads();
  suffix_scan(s, 2048, tid);
  for (int i = tid; i < 2048; i += 1024) {
    uint32 SG = (i + 1 < 2048) ? s[i + 1] : 0u;  // count strictly greater
    if (SG <= kk0 && kk0 < s[i]) { sel[0] = (uint32)i; sel[1] = kk0 - SG; }
  }
  __syncthreads();
  const uint32 B1 = sel[0];
  const uint32 k1 = sel[1];
  __syncthreads();

  // ---- Level 2: bits 20..10 (mantissa bits: well-spread, plain atomics) ----
  s[tid] = 0; s[tid + 1024] = 0;
  __syncthreads();
  for (int i = tid; i < N4; i += 1024) {
    float4 x = ce4[i];
    uint32 u0 = __float_as_uint(x.x), u1 = __float_as_uint(x.y);
    uint32 u2 = __float_as_uint(x.z), u3 = __float_as_uint(x.w);
    if ((u0 >> 21) == B1) atomicAdd(&s[(u0 >> 10) & 2047u], 1u);
    if ((u1 >> 21) == B1) atomicAdd(&s[(u1 >> 10) & 2047u], 1u);
    if ((u2 >> 21) == B1) atomicAdd(&s[(u2 >> 10) & 2047u], 1u);
    if ((u3 >> 21) == B1) atomicAdd(&s[(u3 >> 10) & 2047u], 1u);
  }
  __syncthreads();
  suffix_scan(s, 2048, tid);
  for (int i = tid; i < 2048; i += 1024) {
    uint32 SG = (i + 1 < 2048) ? s[i + 1] : 0u;
    if (SG <= k1 && k1 < s[i]) { sel[0] = (uint32)i; sel[1] = k1 - SG; }
  }
  __syncthreads();
  const uint32 B2 = sel[0];
  const uint32 k2 = sel[1];
  __syncthreads();

  // ---- Level 3: bits 9..0 ----
  s[tid] = 0;
  __syncthreads();
  const uint32 pre = (B1 << 11) | B2;
  for (int i = tid; i < N4; i += 1024) {
    float4 x = ce4[i];
    uint32 u0 = __float_as_uint(x.x), u1 = __float_as_uint(x.y);
    uint32 u2 = __float_as_uint(x.z), u3 = __float_as_uint(x.w);
    if ((u0 >> 10) == pre) atomicAdd(&s[u0 & 1023u], 1u);
    if ((u1 >> 10) == pre) atomicAdd(&s[u1 & 1023u], 1u);
    if ((u2 >> 10) == pre) atomicAdd(&s[u2 & 1023u], 1u);
    if ((u3 >> 10) == pre) atomicAdd(&s[u3 & 1023u], 1u);
  }
  __syncthreads();
  suffix_scan(s, 1024, tid);
  {
    int i = tid;  // 1024 bins, 1024 threads
    uint32 SG = (i + 1 < 1024) ? s[i + 1] : 0u;
    if (SG <= k2 && k2 < s[i]) sel[0] = (uint32)i;
  }
  __syncthreads();
  const uint32 lam_u = (pre << 10) | sel[0];

  // ---- Sum of all ce >= lam (bit order == value order for ce >= 0) ----
  double acc = 0.0;
  for (int i = tid; i < N4; i += 1024) {
    float4 x = ce4[i];
    if (__float_as_uint(x.x) >= lam_u) acc += (double)x.x;
    if (__float_as_uint(x.y) >= lam_u) acc += (double)x.y;
    if (__float_as_uint(x.z) >= lam_u) acc += (double)x.z;
    if (__float_as_uint(x.w) >= lam_u) acc += (double)x.w;
  }
#pragma unroll
  for (int off = 1; off < 64; off <<= 1) acc += __shfl_xor(acc, off);
  if ((tid & 63) == 0) wsum[tid >> 6] = acc;
  __syncthreads();
  if (tid == 0) {
    double tsum = 0.0;
    for (int i = 0; i < 16; ++i) tsum += wsum[i];
    out[0] = (float)(tsum / (double)N);
  }
}

extern "C" void kernel_launch(void* const* d_in, const int* in_sizes, int n_in,
                              void* d_out, int out_size, void* d_ws, size_t ws_size,
                              hipStream_t stream) {
  const float* logits = (const float*)d_in[0];
  const int* target = (const int*)d_in[1];
  float* out = (float*)d_out;

  const int N = in_sizes[1];            // 32768
  const int C = in_sizes[0] / N;        // 1000

  float* ce = (float*)d_ws;

  // Kernel 1: one 256-thread block per row. No atomics, no histogram.
  ce_kernel<<<N, 256, 0, stream>>>(logits, target, ce, N, C);

  // k = int(N * 0.3)
  int k = (int)((double)N * 0.3);

  // Kernel 2: single block: histogram + radix refine + filtered mean.
  select_kernel<<<1, 1024, 0, stream>>>(ce, out, N, k);
}